// Round 13
// baseline (177.385 us; speedup 1.0000x reference)
//
#include <hip/hip_runtime.h>
#include <math.h>

// Round-13: MEASUREMENT ROUND. Byte-identical round-10 kernels; qr_kernel
// launched 3x (idempotent) to decompose dur = 3*qr + mm + oh against the
// round-10 baseline 135.0 = qr + mm + oh  =>  qr = (dur - 135)/2.

#define QR_M 512
#define QR_N 26
#define OUTC 512
#define LDP 30   // LDS row stride (floats): even (8B-aligned float2)

using half8_t = __attribute__((ext_vector_type(8))) _Float16;
using f32x4   = __attribute__((ext_vector_type(4))) float;

__global__ __launch_bounds__(512) void qr_kernel(const float* __restrict__ w,
                                                 _Float16* __restrict__ qf) {
  const int tid  = threadIdx.x;
  const int lane = tid & 63;
  const int wid  = tid >> 6;

  __shared__ float As[QR_M][LDP];
  __shared__ float Gs[QR_N][LDP];
  __shared__ float Rt[QR_N][LDP];
  __shared__ float Gp[4][91][4];

  // ---- Phase 1: stage A ----
  {
    const float2* wp = reinterpret_cast<const float2*>(w + (size_t)tid * QR_N);
    float2 v[13];
#pragma unroll
    for (int i = 0; i < 13; ++i) v[i] = wp[i];
#pragma unroll
    for (int i = 0; i < 13; ++i) {
      As[tid][2 * i]     = v[i].x + 1e-8f;
      As[tid][2 * i + 1] = v[i].y + 1e-8f;
    }
  }
  __syncthreads();

  // ---- Phase 2a: partial Gram (364 threads) ----
  if (tid < 364) {
    const int chunk = tid / 91;
    const int blk   = tid - chunk * 91;
    int cb = 0, rem = blk;
    while (rem >= 13 - cb) { rem -= 13 - cb; ++cb; }
    const int db = cb + rem;
    const int c0 = 2 * cb, d0 = 2 * db;
    float s00 = 0.f, s01 = 0.f, s10 = 0.f, s11 = 0.f;
    const int r0 = chunk * 128;
    for (int r = r0; r < r0 + 128; ++r) {
      const float2 ac = *reinterpret_cast<const float2*>(&As[r][c0]);
      const float2 ad = *reinterpret_cast<const float2*>(&As[r][d0]);
      s00 += ac.x * ad.x; s01 += ac.x * ad.y;
      s10 += ac.y * ad.x; s11 += ac.y * ad.y;
    }
    Gp[chunk][blk][0] = s00; Gp[chunk][blk][1] = s01;
    Gp[chunk][blk][2] = s10; Gp[chunk][blk][3] = s11;
  }
  __syncthreads();

  // ---- Phase 2b: combine partials -> Gs ----
  if (tid < 364) {
    const int blk = tid >> 2;
    const int v   = tid & 3;
    int cb = 0, rem = blk;
    while (rem >= 13 - cb) { rem -= 13 - cb; ++cb; }
    const int db = cb + rem;
    const float s = Gp[0][blk][v] + Gp[1][blk][v] + Gp[2][blk][v] + Gp[3][blk][v];
    const int c = 2 * cb + (v >> 1);
    const int d = 2 * db + (v & 1);
    Gs[c][d] = s;
    Gs[d][c] = s;
  }
  __syncthreads();

  // ---- Phase 3: 26-step recursion, wave 0, registers + shfl ----
  if (wid == 0) {
    const int c  = lane;
    const int cm = (c < QR_N) ? c : (QR_N - 1);
    float gcol[QR_N], tcol[QR_N], rcol[QR_N];
#pragma unroll
    for (int r = 0; r < QR_N; ++r) gcol[r] = Gs[r][cm];
#pragma unroll
    for (int r = 0; r < QR_N; ++r) tcol[r] = As[r][cm];
#pragma unroll
    for (int r = 0; r < QR_N; ++r) rcol[r] = 0.0f;

#pragma unroll
    for (int j = 0; j < QR_N; ++j) {
      float tg = gcol[j];
#pragma unroll
      for (int r = 0; r < QR_N; ++r) {
        if (r < j) tg -= __shfl(rcol[r], j) * rcol[r];
      }
      const float nsq   = __shfl(tg, j);
      const float alpha = __shfl(tcol[j], j);
      const float norm  = sqrtf(nsq);
      const float beta  = (alpha >= 0.0f) ? -norm : norm;
      const float tau   = (beta - alpha) / beta;
      const float scale = 1.0f / (alpha - beta);
      const float wc    = (tg - beta * tcol[j]) * scale;
      const float tw    = (c > j) ? (tau * wc) : 0.0f;
      tcol[j] -= tw;
      rcol[j]  = (c == j) ? beta : tcol[j];
#pragma unroll
      for (int rr = 0; rr < QR_N; ++rr) {
        if (rr > j) {
          const float vtop = __shfl(tcol[rr], j) * scale;
          tcol[rr] -= tw * vtop;
        }
      }
      if (c >= j && c < QR_N) Rt[c][j] = rcol[j];
    }
  }
  __syncthreads();

  // ---- Phase 4: per-row solve y * R = A[t,:]; emit f16 [512][32] ----
  float rinv[QR_N];
#pragma unroll
  for (int cc = 0; cc < QR_N; ++cc) rinv[cc] = 1.0f / Rt[cc][cc];

  float y[QR_N];
#pragma unroll
  for (int cc = 0; cc < QR_N; ++cc) y[cc] = As[tid][cc];
#pragma unroll
  for (int cc = 0; cc < QR_N; ++cc) {
    float s = y[cc];
    int k = 0;
#pragma unroll
    for (; k + 1 < cc; k += 2) {
      const float2 rk = *reinterpret_cast<const float2*>(&Rt[cc][k]);
      s -= y[k] * rk.x + y[k + 1] * rk.y;
    }
    if (k < cc) s -= y[k] * Rt[cc][k];
    y[cc] = s * rinv[cc];
  }

  half8_t h0, h1, h2, h3;
#pragma unroll
  for (int e = 0; e < 8; ++e) h0[e] = (_Float16)y[e];
#pragma unroll
  for (int e = 0; e < 8; ++e) h1[e] = (_Float16)y[8 + e];
#pragma unroll
  for (int e = 0; e < 8; ++e) h2[e] = (_Float16)y[16 + e];
  h3[0] = (_Float16)y[24]; h3[1] = (_Float16)y[25];
#pragma unroll
  for (int e = 2; e < 8; ++e) h3[e] = (_Float16)0.0f;
  half8_t* qrow = reinterpret_cast<half8_t*>(qf + (size_t)tid * 32);
  qrow[0] = h0; qrow[1] = h1; qrow[2] = h2; qrow[3] = h3;
}

__global__ __launch_bounds__(256, 4) void dir_matmul(const float* __restrict__ x,
                                                     const _Float16* __restrict__ qf,
                                                     float* __restrict__ out,
                                                     int nblk32) {
  const int tid   = threadIdx.x;
  const int wid   = tid >> 6;
  const int l     = tid & 63;
  const int rloc  = l & 15;
  const int grp   = l >> 4;
  const int k0    = grp * 8;
  const int rhalf = (wid >> 1) * 16;
  const int chalf = (wid & 1) * 256;
  const int t2b   = (wid & 1) * 16;

  __shared__ float tile[4][16 * 132];
  float* tw = tile[wid];

  half8_t bq[16];
#pragma unroll
  for (int t2 = 0; t2 < 16; ++t2)
    bq[t2] = *reinterpret_cast<const half8_t*>(
        qf + (size_t)((t2b + t2) * 16 + rloc) * 32 + k0);

  for (int rb = blockIdx.x; rb < nblk32; rb += gridDim.x) {
    const int row = rb * 32 + rhalf + rloc;
    half8_t av;
    const float* xp = x + (size_t)row * QR_N + k0;
    if (grp < 3) {
#pragma unroll
      for (int e = 0; e < 4; ++e) {
        float2 v = *reinterpret_cast<const float2*>(xp + 2 * e);
        av[2 * e]     = (_Float16)v.x;
        av[2 * e + 1] = (_Float16)v.y;
      }
    } else {
      float2 v = *reinterpret_cast<const float2*>(xp);
      av[0] = (_Float16)v.x; av[1] = (_Float16)v.y;
#pragma unroll
      for (int e = 2; e < 8; ++e) av[e] = (_Float16)0.0f;
    }

#pragma unroll
    for (int cc = 0; cc < 2; ++cc) {
#pragma unroll
      for (int tt = 0; tt < 8; ++tt) {
        f32x4 acc = {0.0f, 0.0f, 0.0f, 0.0f};
        acc = __builtin_amdgcn_mfma_f32_16x16x32_f16(av, bq[cc * 8 + tt], acc, 0, 0, 0);
#pragma unroll
        for (int j = 0; j < 4; ++j)
          tw[(grp * 4 + j) * 132 + tt * 16 + rloc] = acc[j];
      }
      __syncthreads();
#pragma unroll
      for (int it = 0; it < 8; ++it) {
        const int r  = it * 2 + (l >> 5);
        const int cg = l & 31;
        f32x4 v = *reinterpret_cast<const f32x4*>(&tw[r * 132 + 4 * cg]);
        *reinterpret_cast<f32x4*>(
            out + (size_t)(rb * 32 + rhalf + r) * OUTC + chalf + cc * 128 + 4 * cg) = v;
      }
      __syncthreads();
    }
  }
}

extern "C" void kernel_launch(void* const* d_in, const int* in_sizes, int n_in,
                              void* d_out, int out_size, void* d_ws, size_t ws_size,
                              hipStream_t stream) {
  const float* input  = (const float*)d_in[0];   // [B, 26] f32
  const float* weight = (const float*)d_in[1];   // [512, 26] f32
  float* out = (float*)d_out;                    // [B, 512] f32
  _Float16* qf = (_Float16*)d_ws;                // [512][32] f16 scratch (32 KB)

  const int B = in_sizes[0] / QR_N;              // 262144
  const int nblk32 = B / 32;                     // 8192

  // 3x idempotent qr launches: dur = 3*qr + mm + oh  (R10 baseline: 135.0)
  qr_kernel<<<1, 512, 0, stream>>>(weight, qf);
  qr_kernel<<<1, 512, 0, stream>>>(weight, qf);
  qr_kernel<<<1, 512, 0, stream>>>(weight, qf);
  dir_matmul<<<2048, 256, 0, stream>>>(input, qf, out, nblk32);
}

// Round 14
// 139.007 us; speedup vs baseline: 1.2761x; 1.2761x over previous
//
#include <hip/hip_runtime.h>
#include <math.h>

#define QR_M 512
#define QR_N 26
#define OUTC 512
#define LDP 30   // LDS row stride (floats): even (8B-aligned float2)

using half8_t = __attribute__((ext_vector_type(8))) _Float16;
using f32x4   = __attribute__((ext_vector_type(4))) float;

// ---------------------------------------------------------------------------
// Kernel 1 (round-10-proven, unchanged): Gram-domain Householder QR.
// Ph1 stage A; Ph2 Gram via 2x2-blocked partials; Ph3 26-step recursion on
// wave 0 in registers+shfl (LAPACK slarfg signs, no cross-lane LDS deps);
// Ph4 per-row forward-substitution solve -> Q as f16 [512][32], k-padded.
// Measured (R13 3x-launch decomposition): ~21 us.
// ---------------------------------------------------------------------------
__global__ __launch_bounds__(512) void qr_kernel(const float* __restrict__ w,
                                                 _Float16* __restrict__ qf) {
  const int tid  = threadIdx.x;
  const int lane = tid & 63;
  const int wid  = tid >> 6;

  __shared__ float As[QR_M][LDP];
  __shared__ float Gs[QR_N][LDP];
  __shared__ float Rt[QR_N][LDP];
  __shared__ float Gp[4][91][4];

  // ---- Phase 1: stage A ----
  {
    const float2* wp = reinterpret_cast<const float2*>(w + (size_t)tid * QR_N);
    float2 v[13];
#pragma unroll
    for (int i = 0; i < 13; ++i) v[i] = wp[i];
#pragma unroll
    for (int i = 0; i < 13; ++i) {
      As[tid][2 * i]     = v[i].x + 1e-8f;
      As[tid][2 * i + 1] = v[i].y + 1e-8f;
    }
  }
  __syncthreads();

  // ---- Phase 2a: partial Gram (364 threads) ----
  if (tid < 364) {
    const int chunk = tid / 91;
    const int blk   = tid - chunk * 91;
    int cb = 0, rem = blk;
    while (rem >= 13 - cb) { rem -= 13 - cb; ++cb; }
    const int db = cb + rem;
    const int c0 = 2 * cb, d0 = 2 * db;
    float s00 = 0.f, s01 = 0.f, s10 = 0.f, s11 = 0.f;
    const int r0 = chunk * 128;
    for (int r = r0; r < r0 + 128; ++r) {
      const float2 ac = *reinterpret_cast<const float2*>(&As[r][c0]);
      const float2 ad = *reinterpret_cast<const float2*>(&As[r][d0]);
      s00 += ac.x * ad.x; s01 += ac.x * ad.y;
      s10 += ac.y * ad.x; s11 += ac.y * ad.y;
    }
    Gp[chunk][blk][0] = s00; Gp[chunk][blk][1] = s01;
    Gp[chunk][blk][2] = s10; Gp[chunk][blk][3] = s11;
  }
  __syncthreads();

  // ---- Phase 2b: combine partials -> Gs ----
  if (tid < 364) {
    const int blk = tid >> 2;
    const int v   = tid & 3;
    int cb = 0, rem = blk;
    while (rem >= 13 - cb) { rem -= 13 - cb; ++cb; }
    const int db = cb + rem;
    const float s = Gp[0][blk][v] + Gp[1][blk][v] + Gp[2][blk][v] + Gp[3][blk][v];
    const int c = 2 * cb + (v >> 1);
    const int d = 2 * db + (v & 1);
    Gs[c][d] = s;
    Gs[d][c] = s;
  }
  __syncthreads();

  // ---- Phase 3: 26-step recursion, wave 0, registers + shfl ----
  if (wid == 0) {
    const int c  = lane;
    const int cm = (c < QR_N) ? c : (QR_N - 1);
    float gcol[QR_N], tcol[QR_N], rcol[QR_N];
#pragma unroll
    for (int r = 0; r < QR_N; ++r) gcol[r] = Gs[r][cm];
#pragma unroll
    for (int r = 0; r < QR_N; ++r) tcol[r] = As[r][cm];
#pragma unroll
    for (int r = 0; r < QR_N; ++r) rcol[r] = 0.0f;

#pragma unroll
    for (int j = 0; j < QR_N; ++j) {
      float tg = gcol[j];
#pragma unroll
      for (int r = 0; r < QR_N; ++r) {
        if (r < j) tg -= __shfl(rcol[r], j) * rcol[r];
      }
      const float nsq   = __shfl(tg, j);
      const float alpha = __shfl(tcol[j], j);
      const float norm  = sqrtf(nsq);
      const float beta  = (alpha >= 0.0f) ? -norm : norm;  // -sign(alpha)*norm
      const float tau   = (beta - alpha) / beta;
      const float scale = 1.0f / (alpha - beta);
      const float wc    = (tg - beta * tcol[j]) * scale;
      const float tw    = (c > j) ? (tau * wc) : 0.0f;
      tcol[j] -= tw;
      rcol[j]  = (c == j) ? beta : tcol[j];
#pragma unroll
      for (int rr = 0; rr < QR_N; ++rr) {
        if (rr > j) {
          const float vtop = __shfl(tcol[rr], j) * scale;
          tcol[rr] -= tw * vtop;
        }
      }
      if (c >= j && c < QR_N) Rt[c][j] = rcol[j];
    }
  }
  __syncthreads();

  // ---- Phase 4: per-row solve y * R = A[t,:]; emit f16 [512][32] ----
  float rinv[QR_N];
#pragma unroll
  for (int cc = 0; cc < QR_N; ++cc) rinv[cc] = 1.0f / Rt[cc][cc];

  float y[QR_N];
#pragma unroll
  for (int cc = 0; cc < QR_N; ++cc) y[cc] = As[tid][cc];
#pragma unroll
  for (int cc = 0; cc < QR_N; ++cc) {
    float s = y[cc];
    int k = 0;
#pragma unroll
    for (; k + 1 < cc; k += 2) {
      const float2 rk = *reinterpret_cast<const float2*>(&Rt[cc][k]);
      s -= y[k] * rk.x + y[k + 1] * rk.y;
    }
    if (k < cc) s -= y[k] * Rt[cc][k];
    y[cc] = s * rinv[cc];
  }

  half8_t h0, h1, h2, h3;
#pragma unroll
  for (int e = 0; e < 8; ++e) h0[e] = (_Float16)y[e];
#pragma unroll
  for (int e = 0; e < 8; ++e) h1[e] = (_Float16)y[8 + e];
#pragma unroll
  for (int e = 0; e < 8; ++e) h2[e] = (_Float16)y[16 + e];
  h3[0] = (_Float16)y[24]; h3[1] = (_Float16)y[25];
#pragma unroll
  for (int e = 2; e < 8; ++e) h3[e] = (_Float16)0.0f;
  half8_t* qrow = reinterpret_cast<half8_t*>(qf + (size_t)tid * 32);
  qrow[0] = h0; qrow[1] = h1; qrow[2] = h2; qrow[3] = h3;
}

// ---------------------------------------------------------------------------
// Kernel 2: MFMA matmul, BARRIER-FREE epilogue. `tile` is per-wave private
// (tile[wid]) so the old __syncthreads pair per cc-chunk only forced a
// vmcnt(0) store-drain 4x per iteration (R13 decomposition: mm ~105 us,
// ~20 us above the 85 us write floor). Wave-local LDS RAW is ordered by
// compiler lgkmcnt waits; WAR across cc-chunks by the in-order per-wave DS
// pipe. Stores now pipeline across iterations.
// ---------------------------------------------------------------------------
__global__ __launch_bounds__(256, 4) void dir_matmul(const float* __restrict__ x,
                                                     const _Float16* __restrict__ qf,
                                                     float* __restrict__ out,
                                                     int nblk32) {
  const int tid   = threadIdx.x;
  const int wid   = tid >> 6;
  const int l     = tid & 63;
  const int rloc  = l & 15;
  const int grp   = l >> 4;
  const int k0    = grp * 8;
  const int rhalf = (wid >> 1) * 16;
  const int chalf = (wid & 1) * 256;
  const int t2b   = (wid & 1) * 16;

  __shared__ float tile[4][16 * 132];
  float* tw = tile[wid];

  half8_t bq[16];
#pragma unroll
  for (int t2 = 0; t2 < 16; ++t2)
    bq[t2] = *reinterpret_cast<const half8_t*>(
        qf + (size_t)((t2b + t2) * 16 + rloc) * 32 + k0);

  for (int rb = blockIdx.x; rb < nblk32; rb += gridDim.x) {
    const int row = rb * 32 + rhalf + rloc;
    half8_t av;
    const float* xp = x + (size_t)row * QR_N + k0;
    if (grp < 3) {
#pragma unroll
      for (int e = 0; e < 4; ++e) {
        float2 v = *reinterpret_cast<const float2*>(xp + 2 * e);
        av[2 * e]     = (_Float16)v.x;
        av[2 * e + 1] = (_Float16)v.y;
      }
    } else {
      float2 v = *reinterpret_cast<const float2*>(xp);
      av[0] = (_Float16)v.x; av[1] = (_Float16)v.y;
#pragma unroll
      for (int e = 2; e < 8; ++e) av[e] = (_Float16)0.0f;
    }

#pragma unroll
    for (int cc = 0; cc < 2; ++cc) {
#pragma unroll
      for (int tt = 0; tt < 8; ++tt) {
        f32x4 acc = {0.0f, 0.0f, 0.0f, 0.0f};
        acc = __builtin_amdgcn_mfma_f32_16x16x32_f16(av, bq[cc * 8 + tt], acc, 0, 0, 0);
#pragma unroll
        for (int j = 0; j < 4; ++j)
          tw[(grp * 4 + j) * 132 + tt * 16 + rloc] = acc[j];
      }
      // no barrier: tile[wid] is wave-private; lgkmcnt orders RAW, in-order
      // DS pipe orders the next chunk's WAR.
#pragma unroll
      for (int it = 0; it < 8; ++it) {
        const int r  = it * 2 + (l >> 5);
        const int cg = l & 31;
        f32x4 v = *reinterpret_cast<const f32x4*>(&tw[r * 132 + 4 * cg]);
        *reinterpret_cast<f32x4*>(
            out + (size_t)(rb * 32 + rhalf + r) * OUTC + chalf + cc * 128 + 4 * cg) = v;
      }
    }
  }
}

extern "C" void kernel_launch(void* const* d_in, const int* in_sizes, int n_in,
                              void* d_out, int out_size, void* d_ws, size_t ws_size,
                              hipStream_t stream) {
  const float* input  = (const float*)d_in[0];   // [B, 26] f32
  const float* weight = (const float*)d_in[1];   // [512, 26] f32
  float* out = (float*)d_out;                    // [B, 512] f32
  _Float16* qf = (_Float16*)d_ws;                // [512][32] f16 scratch (32 KB)

  const int B = in_sizes[0] / QR_N;              // 262144
  const int nblk32 = B / 32;                     // 8192

  qr_kernel<<<1, 512, 0, stream>>>(weight, qf);
  dir_matmul<<<2048, 256, 0, stream>>>(input, qf, out, nblk32);
}

// Round 15
// 138.466 us; speedup vs baseline: 1.2811x; 1.0039x over previous
//
#include <hip/hip_runtime.h>
#include <math.h>

#define QR_M 512
#define QR_N 26
#define OUTC 512
#define LDP 30   // LDS row stride (floats): even (8B-aligned float2)

using half8_t = __attribute__((ext_vector_type(8))) _Float16;
using f32x4   = __attribute__((ext_vector_type(4))) float;

// ---------------------------------------------------------------------------
// K0 (R12-proven): partial Gram. Block b sums rows 32b..32b+31 of A = w+1e-8
// into gp[b][351] (upper-tri pairs). 16 blocks in parallel.
// ---------------------------------------------------------------------------
__global__ __launch_bounds__(448) void gram_part(const float* __restrict__ w,
                                                 float* __restrict__ gp) {
  __shared__ float Ab[32][27];
  const int tid = threadIdx.x;
  const int b   = blockIdx.x;
  if (tid < 416) {
    const int r  = tid / 13;
    const int c2 = tid - r * 13;
    const float2 v = *reinterpret_cast<const float2*>(
        w + (size_t)(b * 32 + r) * QR_N + 2 * c2);
    Ab[r][2 * c2]     = v.x + 1e-8f;
    Ab[r][2 * c2 + 1] = v.y + 1e-8f;
  }
  __syncthreads();
  if (tid < 351) {
    int cb = 0, rem = tid;
    while (rem >= QR_N - cb) { rem -= QR_N - cb; ++cb; }
    const int d = cb + rem;
    float s = 0.0f;
#pragma unroll
    for (int r = 0; r < 32; ++r) s += Ab[r][cb] * Ab[r][d];
    gp[b * 351 + tid] = s;
  }
}

// ---------------------------------------------------------------------------
// K1: combine Gram partials -> recursion -> per-row solve -> Q (f16).
// 512 threads. y-row global loads issued FIRST (hide under combine/recursion).
// 351 threads combine gp (16 partials each, fixed order = R12's determinism).
// Wave 0: R10-proven regs+shfl 26-step Householder recursion (LAPACK slarfg
// signs), tcol init from L1-hot w; writes Rt[c][j]=R[j][c] (write-only LDS).
// All 512: forward-substitution solve y*R = A[row,:] (cond~1.6 -> ~1e-6),
// emit Q as f16 [512][32], k=26..31 zero-padded (MFMA B^T layout).
// ---------------------------------------------------------------------------
__global__ __launch_bounds__(512) void qr_solve(const float* __restrict__ w,
                                                const float* __restrict__ gp,
                                                _Float16* __restrict__ qf) {
  const int tid  = threadIdx.x;
  const int lane = tid & 63;
  const int wid  = tid >> 6;

  __shared__ float Gs[QR_N][LDP];
  __shared__ float Rt[QR_N][LDP];

  // ---- issue own-row loads early ----
  float y[QR_N];
  {
    const float2* wp = reinterpret_cast<const float2*>(w + (size_t)tid * QR_N);
    float2 v[13];
#pragma unroll
    for (int i = 0; i < 13; ++i) v[i] = wp[i];
#pragma unroll
    for (int i = 0; i < 13; ++i) {
      y[2 * i]     = v[i].x + 1e-8f;
      y[2 * i + 1] = v[i].y + 1e-8f;
    }
  }

  // ---- combine partials -> Gs (351 threads, fixed order) ----
  if (tid < 351) {
    float acc = 0.0f;
#pragma unroll
    for (int b = 0; b < 16; ++b) acc += gp[b * 351 + tid];
    int cb = 0, rem = tid;
    while (rem >= QR_N - cb) { rem -= QR_N - cb; ++cb; }
    const int d = cb + rem;
    Gs[cb][d] = acc;
    Gs[d][cb] = acc;
  }
  __syncthreads();

  // ---- recursion: wave 0, registers + shfl (R10-proven) ----
  if (wid == 0) {
    const int c  = lane;
    const int cm = (c < QR_N) ? c : (QR_N - 1);  // lanes 26..63 carry dummies
    float gcol[QR_N], tcol[QR_N], rcol[QR_N];
#pragma unroll
    for (int r = 0; r < QR_N; ++r) gcol[r] = Gs[r][cm];
#pragma unroll
    for (int r = 0; r < QR_N; ++r) tcol[r] = w[r * QR_N + cm] + 1e-8f;
#pragma unroll
    for (int r = 0; r < QR_N; ++r) rcol[r] = 0.0f;

#pragma unroll
    for (int j = 0; j < QR_N; ++j) {
      float tg = gcol[j];
#pragma unroll
      for (int r = 0; r < QR_N; ++r) {
        if (r < j) tg -= __shfl(rcol[r], j) * rcol[r];
      }
      const float nsq   = __shfl(tg, j);
      const float alpha = __shfl(tcol[j], j);
      const float norm  = sqrtf(nsq);
      const float beta  = (alpha >= 0.0f) ? -norm : norm;  // -sign(alpha)*norm
      const float tau   = (beta - alpha) / beta;
      const float scale = 1.0f / (alpha - beta);
      const float wc    = (tg - beta * tcol[j]) * scale;
      const float tw    = (c > j) ? (tau * wc) : 0.0f;
      tcol[j] -= tw;
      rcol[j]  = (c == j) ? beta : tcol[j];
#pragma unroll
      for (int rr = 0; rr < QR_N; ++rr) {
        if (rr > j) {
          const float vtop = __shfl(tcol[rr], j) * scale;
          tcol[rr] -= tw * vtop;
        }
      }
      if (c >= j && c < QR_N) Rt[c][j] = rcol[j];  // write-only LDS
    }
  }
  __syncthreads();

  // ---- per-row solve y * R = A[row,:]; emit f16 [512][32] ----
  float rinv[QR_N];
#pragma unroll
  for (int cc = 0; cc < QR_N; ++cc) rinv[cc] = 1.0f / Rt[cc][cc];

#pragma unroll
  for (int cc = 0; cc < QR_N; ++cc) {
    float s = y[cc];
    int k = 0;
#pragma unroll
    for (; k + 1 < cc; k += 2) {
      const float2 rk = *reinterpret_cast<const float2*>(&Rt[cc][k]);  // bcast
      s -= y[k] * rk.x + y[k + 1] * rk.y;
    }
    if (k < cc) s -= y[k] * Rt[cc][k];
    y[cc] = s * rinv[cc];
  }

  half8_t h0, h1, h2, h3;
#pragma unroll
  for (int e = 0; e < 8; ++e) h0[e] = (_Float16)y[e];
#pragma unroll
  for (int e = 0; e < 8; ++e) h1[e] = (_Float16)y[8 + e];
#pragma unroll
  for (int e = 0; e < 8; ++e) h2[e] = (_Float16)y[16 + e];
  h3[0] = (_Float16)y[24]; h3[1] = (_Float16)y[25];
#pragma unroll
  for (int e = 2; e < 8; ++e) h3[e] = (_Float16)0.0f;
  half8_t* qrow = reinterpret_cast<half8_t*>(qf + (size_t)tid * 32);
  qrow[0] = h0; qrow[1] = h1; qrow[2] = h2; qrow[3] = h3;
}

// ---------------------------------------------------------------------------
// K2 (byte-identical R10, 135.0-us-proven): MFMA matmul with LDS-transposed
// epilogue and per-chunk barriers (R14 showed removing them regresses).
// ---------------------------------------------------------------------------
__global__ __launch_bounds__(256, 4) void dir_matmul(const float* __restrict__ x,
                                                     const _Float16* __restrict__ qf,
                                                     float* __restrict__ out,
                                                     int nblk32) {
  const int tid   = threadIdx.x;
  const int wid   = tid >> 6;
  const int l     = tid & 63;
  const int rloc  = l & 15;
  const int grp   = l >> 4;
  const int k0    = grp * 8;
  const int rhalf = (wid >> 1) * 16;
  const int chalf = (wid & 1) * 256;
  const int t2b   = (wid & 1) * 16;

  __shared__ float tile[4][16 * 132];
  float* tw = tile[wid];

  half8_t bq[16];
#pragma unroll
  for (int t2 = 0; t2 < 16; ++t2)
    bq[t2] = *reinterpret_cast<const half8_t*>(
        qf + (size_t)((t2b + t2) * 16 + rloc) * 32 + k0);

  for (int rb = blockIdx.x; rb < nblk32; rb += gridDim.x) {
    const int row = rb * 32 + rhalf + rloc;
    half8_t av;
    const float* xp = x + (size_t)row * QR_N + k0;
    if (grp < 3) {
#pragma unroll
      for (int e = 0; e < 4; ++e) {
        float2 v = *reinterpret_cast<const float2*>(xp + 2 * e);
        av[2 * e]     = (_Float16)v.x;
        av[2 * e + 1] = (_Float16)v.y;
      }
    } else {
      float2 v = *reinterpret_cast<const float2*>(xp);
      av[0] = (_Float16)v.x; av[1] = (_Float16)v.y;
#pragma unroll
      for (int e = 2; e < 8; ++e) av[e] = (_Float16)0.0f;
    }

#pragma unroll
    for (int cc = 0; cc < 2; ++cc) {
#pragma unroll
      for (int tt = 0; tt < 8; ++tt) {
        f32x4 acc = {0.0f, 0.0f, 0.0f, 0.0f};
        acc = __builtin_amdgcn_mfma_f32_16x16x32_f16(av, bq[cc * 8 + tt], acc, 0, 0, 0);
#pragma unroll
        for (int j = 0; j < 4; ++j)
          tw[(grp * 4 + j) * 132 + tt * 16 + rloc] = acc[j];
      }
      __syncthreads();
#pragma unroll
      for (int it = 0; it < 8; ++it) {
        const int r  = it * 2 + (l >> 5);
        const int cg = l & 31;
        f32x4 v = *reinterpret_cast<const f32x4*>(&tw[r * 132 + 4 * cg]);
        *reinterpret_cast<f32x4*>(
            out + (size_t)(rb * 32 + rhalf + r) * OUTC + chalf + cc * 128 + 4 * cg) = v;
      }
      __syncthreads();
    }
  }
}

extern "C" void kernel_launch(void* const* d_in, const int* in_sizes, int n_in,
                              void* d_out, int out_size, void* d_ws, size_t ws_size,
                              hipStream_t stream) {
  const float* input  = (const float*)d_in[0];   // [B, 26] f32
  const float* weight = (const float*)d_in[1];   // [512, 26] f32
  float* out = (float*)d_out;                    // [B, 512] f32

  float*    gp = (float*)d_ws;                       // 16*351 f32 = 22.5 KB
  _Float16* qf = (_Float16*)((char*)d_ws + 24576);   // [512][32] f16 = 32 KB

  const int B = in_sizes[0] / QR_N;              // 262144
  const int nblk32 = B / 32;                     // 8192

  gram_part<<<16, 448, 0, stream>>>(weight, gp);
  qr_solve<<<1, 512, 0, stream>>>(weight, gp, qf);
  dir_matmul<<<2048, 256, 0, stream>>>(input, qf, out, nblk32);
}

// Round 16
// 122.779 us; speedup vs baseline: 1.4448x; 1.1278x over previous
//
#include <hip/hip_runtime.h>
#include <math.h>

#define QR_M 512
#define QR_N 26
#define OUTC 512
#define LDP 30   // LDS row stride (floats): even (8B-aligned float2)

using half8_t = __attribute__((ext_vector_type(8))) _Float16;
using f32x4   = __attribute__((ext_vector_type(4))) float;

// ---------------------------------------------------------------------------
// Kernel 1 (round-10-proven, byte-identical): Gram-domain Householder QR.
// Ph1 stage A; Ph2 Gram via 2x2-blocked partials; Ph3 26-step recursion on
// wave 0 in registers+shfl (LAPACK slarfg signs); Ph4 per-row forward-
// substitution solve -> Q as f16 [512][32], k-padded. ~18 us exec.
// ---------------------------------------------------------------------------
__global__ __launch_bounds__(512) void qr_kernel(const float* __restrict__ w,
                                                 _Float16* __restrict__ qf) {
  const int tid  = threadIdx.x;
  const int lane = tid & 63;
  const int wid  = tid >> 6;

  __shared__ float As[QR_M][LDP];
  __shared__ float Gs[QR_N][LDP];
  __shared__ float Rt[QR_N][LDP];
  __shared__ float Gp[4][91][4];

  // ---- Phase 1: stage A ----
  {
    const float2* wp = reinterpret_cast<const float2*>(w + (size_t)tid * QR_N);
    float2 v[13];
#pragma unroll
    for (int i = 0; i < 13; ++i) v[i] = wp[i];
#pragma unroll
    for (int i = 0; i < 13; ++i) {
      As[tid][2 * i]     = v[i].x + 1e-8f;
      As[tid][2 * i + 1] = v[i].y + 1e-8f;
    }
  }
  __syncthreads();

  // ---- Phase 2a: partial Gram (364 threads) ----
  if (tid < 364) {
    const int chunk = tid / 91;
    const int blk   = tid - chunk * 91;
    int cb = 0, rem = blk;
    while (rem >= 13 - cb) { rem -= 13 - cb; ++cb; }
    const int db = cb + rem;
    const int c0 = 2 * cb, d0 = 2 * db;
    float s00 = 0.f, s01 = 0.f, s10 = 0.f, s11 = 0.f;
    const int r0 = chunk * 128;
    for (int r = r0; r < r0 + 128; ++r) {
      const float2 ac = *reinterpret_cast<const float2*>(&As[r][c0]);
      const float2 ad = *reinterpret_cast<const float2*>(&As[r][d0]);
      s00 += ac.x * ad.x; s01 += ac.x * ad.y;
      s10 += ac.y * ad.x; s11 += ac.y * ad.y;
    }
    Gp[chunk][blk][0] = s00; Gp[chunk][blk][1] = s01;
    Gp[chunk][blk][2] = s10; Gp[chunk][blk][3] = s11;
  }
  __syncthreads();

  // ---- Phase 2b: combine partials -> Gs ----
  if (tid < 364) {
    const int blk = tid >> 2;
    const int v   = tid & 3;
    int cb = 0, rem = blk;
    while (rem >= 13 - cb) { rem -= 13 - cb; ++cb; }
    const int db = cb + rem;
    const float s = Gp[0][blk][v] + Gp[1][blk][v] + Gp[2][blk][v] + Gp[3][blk][v];
    const int c = 2 * cb + (v >> 1);
    const int d = 2 * db + (v & 1);
    Gs[c][d] = s;
    Gs[d][c] = s;
  }
  __syncthreads();

  // ---- Phase 3: 26-step recursion, wave 0, registers + shfl ----
  if (wid == 0) {
    const int c  = lane;
    const int cm = (c < QR_N) ? c : (QR_N - 1);
    float gcol[QR_N], tcol[QR_N], rcol[QR_N];
#pragma unroll
    for (int r = 0; r < QR_N; ++r) gcol[r] = Gs[r][cm];
#pragma unroll
    for (int r = 0; r < QR_N; ++r) tcol[r] = As[r][cm];
#pragma unroll
    for (int r = 0; r < QR_N; ++r) rcol[r] = 0.0f;

#pragma unroll
    for (int j = 0; j < QR_N; ++j) {
      float tg = gcol[j];
#pragma unroll
      for (int r = 0; r < QR_N; ++r) {
        if (r < j) tg -= __shfl(rcol[r], j) * rcol[r];
      }
      const float nsq   = __shfl(tg, j);
      const float alpha = __shfl(tcol[j], j);
      const float norm  = sqrtf(nsq);
      const float beta  = (alpha >= 0.0f) ? -norm : norm;  // -sign(alpha)*norm
      const float tau   = (beta - alpha) / beta;
      const float scale = 1.0f / (alpha - beta);
      const float wc    = (tg - beta * tcol[j]) * scale;
      const float tw    = (c > j) ? (tau * wc) : 0.0f;
      tcol[j] -= tw;
      rcol[j]  = (c == j) ? beta : tcol[j];
#pragma unroll
      for (int rr = 0; rr < QR_N; ++rr) {
        if (rr > j) {
          const float vtop = __shfl(tcol[rr], j) * scale;
          tcol[rr] -= tw * vtop;
        }
      }
      if (c >= j && c < QR_N) Rt[c][j] = rcol[j];
    }
  }
  __syncthreads();

  // ---- Phase 4: per-row solve y * R = A[t,:]; emit f16 [512][32] ----
  float rinv[QR_N];
#pragma unroll
  for (int cc = 0; cc < QR_N; ++cc) rinv[cc] = 1.0f / Rt[cc][cc];

  float y[QR_N];
#pragma unroll
  for (int cc = 0; cc < QR_N; ++cc) y[cc] = As[tid][cc];
#pragma unroll
  for (int cc = 0; cc < QR_N; ++cc) {
    float s = y[cc];
    int k = 0;
#pragma unroll
    for (; k + 1 < cc; k += 2) {
      const float2 rk = *reinterpret_cast<const float2*>(&Rt[cc][k]);
      s -= y[k] * rk.x + y[k + 1] * rk.y;
    }
    if (k < cc) s -= y[k] * Rt[cc][k];
    y[cc] = s * rinv[cc];
  }

  half8_t h0, h1, h2, h3;
#pragma unroll
  for (int e = 0; e < 8; ++e) h0[e] = (_Float16)y[e];
#pragma unroll
  for (int e = 0; e < 8; ++e) h1[e] = (_Float16)y[8 + e];
#pragma unroll
  for (int e = 0; e < 8; ++e) h2[e] = (_Float16)y[16 + e];
  h3[0] = (_Float16)y[24]; h3[1] = (_Float16)y[25];
#pragma unroll
  for (int e = 2; e < 8; ++e) h3[e] = (_Float16)0.0f;
  half8_t* qrow = reinterpret_cast<half8_t*>(qf + (size_t)tid * 32);
  qrow[0] = h0; qrow[1] = h1; qrow[2] = h2; qrow[3] = h3;
}

// ---------------------------------------------------------------------------
// Kernel 2: R10 MFMA matmul + LDS-transposed epilogue, with NON-TEMPORAL
// output stores (single change). out is write-once-never-read; nt stops L2
// from retaining its lines, protecting the x read stream and qf from
// eviction and avoiding dirty-line churn on the 537 MB write path.
// ---------------------------------------------------------------------------
__global__ __launch_bounds__(256, 4) void dir_matmul(const float* __restrict__ x,
                                                     const _Float16* __restrict__ qf,
                                                     float* __restrict__ out,
                                                     int nblk32) {
  const int tid   = threadIdx.x;
  const int wid   = tid >> 6;
  const int l     = tid & 63;
  const int rloc  = l & 15;
  const int grp   = l >> 4;
  const int k0    = grp * 8;
  const int rhalf = (wid >> 1) * 16;
  const int chalf = (wid & 1) * 256;
  const int t2b   = (wid & 1) * 16;

  __shared__ float tile[4][16 * 132];
  float* tw = tile[wid];

  half8_t bq[16];
#pragma unroll
  for (int t2 = 0; t2 < 16; ++t2)
    bq[t2] = *reinterpret_cast<const half8_t*>(
        qf + (size_t)((t2b + t2) * 16 + rloc) * 32 + k0);

  for (int rb = blockIdx.x; rb < nblk32; rb += gridDim.x) {
    const int row = rb * 32 + rhalf + rloc;
    half8_t av;
    const float* xp = x + (size_t)row * QR_N + k0;
    if (grp < 3) {
#pragma unroll
      for (int e = 0; e < 4; ++e) {
        float2 v = *reinterpret_cast<const float2*>(xp + 2 * e);
        av[2 * e]     = (_Float16)v.x;
        av[2 * e + 1] = (_Float16)v.y;
      }
    } else {
      float2 v = *reinterpret_cast<const float2*>(xp);
      av[0] = (_Float16)v.x; av[1] = (_Float16)v.y;
#pragma unroll
      for (int e = 2; e < 8; ++e) av[e] = (_Float16)0.0f;
    }

#pragma unroll
    for (int cc = 0; cc < 2; ++cc) {
#pragma unroll
      for (int tt = 0; tt < 8; ++tt) {
        f32x4 acc = {0.0f, 0.0f, 0.0f, 0.0f};
        acc = __builtin_amdgcn_mfma_f32_16x16x32_f16(av, bq[cc * 8 + tt], acc, 0, 0, 0);
#pragma unroll
        for (int j = 0; j < 4; ++j)
          tw[(grp * 4 + j) * 132 + tt * 16 + rloc] = acc[j];
      }
      __syncthreads();
#pragma unroll
      for (int it = 0; it < 8; ++it) {
        const int r  = it * 2 + (l >> 5);
        const int cg = l & 31;
        f32x4 v = *reinterpret_cast<const f32x4*>(&tw[r * 132 + 4 * cg]);
        __builtin_nontemporal_store(
            v, reinterpret_cast<f32x4*>(
                   out + (size_t)(rb * 32 + rhalf + r) * OUTC + chalf + cc * 128 + 4 * cg));
      }
      __syncthreads();
    }
  }
}

extern "C" void kernel_launch(void* const* d_in, const int* in_sizes, int n_in,
                              void* d_out, int out_size, void* d_ws, size_t ws_size,
                              hipStream_t stream) {
  const float* input  = (const float*)d_in[0];   // [B, 26] f32
  const float* weight = (const float*)d_in[1];   // [512, 26] f32
  float* out = (float*)d_out;                    // [B, 512] f32
  _Float16* qf = (_Float16*)d_ws;                // [512][32] f16 scratch (32 KB)

  const int B = in_sizes[0] / QR_N;              // 262144
  const int nblk32 = B / 32;                     // 8192

  qr_kernel<<<1, 512, 0, stream>>>(weight, qf);
  dir_matmul<<<2048, 256, 0, stream>>>(input, qf, out, nblk32);
}